// Round 13
// baseline (450.696 us; speedup 1.0000x reference)
//
#include <hip/hip_runtime.h>
#include <hip/hip_bf16.h>

typedef unsigned short u16;
typedef __attribute__((ext_vector_type(8))) short short8;
typedef __attribute__((ext_vector_type(4))) float f32x4;
typedef __attribute__((ext_vector_type(16))) float f32x16;
typedef __attribute__((ext_vector_type(2))) __bf16 bf16x2;

#define NNODES 100000
#define NEDGES 600000
#define NGRAPHS 512
#define HF 128
#define EF 256
#define GB 32       // graphs per head block

// chunk-major LDS planes, 32-node tiles: plane = 32 rows x 16B + 16B pad
// -> stride 264 u16 (528 B = 132 dwords == 4 banks mod 32)
#define PLD 264
__device__ __forceinline__ int cidx(int chunk, int row){ return chunk * PLD + row * 8; }

__device__ __forceinline__ float bfu(u16 u){ return __uint_as_float(((unsigned)u) << 16); }
__device__ __forceinline__ u16 f2bf(float f){
    unsigned u = __float_as_uint(f);
    unsigned r = (u + 0x7fff + ((u >> 16) & 1)) >> 16;
    return (u16)r;
}
// round fp32 to bf16 value (RNE), returned as fp32
__device__ __forceinline__ float rbf(float f){ return bfu(f2bf(f)); }
// HW packed f32->bf16 RNE (v_cvt_pk_bf16_f32 on gfx950)
__device__ __forceinline__ unsigned pack2(float a, float b){
    bf16x2 v = { (__bf16)a, (__bf16)b };
    return __builtin_bit_cast(unsigned, v);
}

#if __has_builtin(__builtin_amdgcn_rcpf)
#define RCP1(x) __builtin_amdgcn_rcpf(x)
#else
#define RCP1(x) (1.f / (x))
#endif

// cheap softplus: log(1+exp(x)) direct — safe for |x| << 80 (values here <~20)
__device__ __forceinline__ float sp_f(float x){
    return __logf(1.f + __expf(x));
}
__device__ __forceinline__ float sig_f(float x){
    return RCP1(1.f + __expf(-x));
}
__device__ __forceinline__ float lf(const void* p, long i, bool f32){
    return f32 ? ((const float*)p)[i] : bfu(((const u16*)p)[i]);
}

// in-register dtype detection: probe 256 u16 of the embed table as bf16
__device__ __forceinline__ bool is_f32(const void* probe){
    const u16* p = (const u16*)probe;
    int lane = threadIdx.x & 63;
    int c = 0;
#pragma unroll
    for (int i = 0; i < 4; i++) c += (fabsf(bfu(p[lane * 4 + i])) > 1.0f) ? 1 : 0;
#pragma unroll
    for (int off = 32; off; off >>= 1) c += __shfl_xor(c, off, 64);
    return c > 8;
}

// ---------------- prep: weight repack + edge count + xsum zero ----------------
// conv weights -> 32x32x16 A-frag order: P[ks][nt32][lane][8]; lane l holds
//   W[k = ks*16 + (l>>5)*8 + j][n = nt32*32 + (l&31)], j=0..7  (W^T as A operand)
// head weights -> 16x16x32 frag order.
// blocks [0,960): conv; [960,1152): head; [1152,3496): edge count;
// [3496,3560): zero xsum (64 blocks x 256 x float4)
__global__ __launch_bounds__(256) void prep_kernel(const void* __restrict__ wg,
                                                   const void* __restrict__ we1,
                                                   const void* __restrict__ we2,
                                                   const void* __restrict__ wp,
                                                   const void* __restrict__ wfc1,
                                                   const void* __restrict__ wfc2,
                                                   u16* __restrict__ pwg,
                                                   u16* __restrict__ pwe1,
                                                   u16* __restrict__ pwe2,
                                                   u16* __restrict__ pwp,
                                                   u16* __restrict__ pf1,
                                                   u16* __restrict__ pf2,
                                                   const void* __restrict__ emb,
                                                   const int* __restrict__ tgt,
                                                   int* __restrict__ counts,
                                                   float* __restrict__ xsum){
    int b = blockIdx.x, t = threadIdx.x;
    if (b < 960) {
        bool f32 = is_f32(emb);
        int i = b * 256 + t;                       // < 3*81920
        int c = i / 81920, r = i % 81920;
        const void* src; u16* dst; int N, KN, l;
        if (r < 16384)      { src = wg;  dst = pwg;  N = HF; KN = 16384; l = r; }
        else if (r < 49152) { src = we1; dst = pwe1; N = EF; KN = 32768; l = r - 16384; }
        else                { src = we2; dst = pwe2; N = HF; KN = 32768; l = r - 49152; }
        int j = l & 7, lane = (l >> 3) & 63, rest = l >> 9;
        int NT = N >> 5;
        int nt = rest % NT, ks = rest / NT;
        int k = ks * 16 + (lane >> 5) * 8 + j;
        int n = nt * 32 + (lane & 31);
        long base = (long)c * KN;
        dst[base + l] = f2bf(lf(src, base + (long)k * N + n, f32));
    } else if (b < 1152) {
        bool f32 = is_f32(emb);
        int i = (b - 960) * 256 + t;               // < 3*16384
        int c = i / 16384, l = i % 16384;
        const void* src = (c == 0) ? wp : (c == 1) ? wfc1 : wfc2;
        u16* dst = (c == 0) ? pwp : (c == 1) ? pf1 : pf2;
        int j = l & 7, lane = (l >> 3) & 63, rest = l >> 9;
        int nt = rest & 7, kt = rest >> 3;         // 16x16 layout, N=128
        int k = kt * 32 + (lane >> 4) * 8 + j;
        int n = nt * 16 + (lane & 15);
        dst[l] = f2bf(lf(src, (long)k * HF + n, f32));
    } else if (b < 3496) {
        int e = (b - 1152) * 256 + t;
        if (e < NEDGES) atomicAdd(&counts[tgt[e]], 1);
    } else {
        int i = (b - 3496) * 256 + t;              // < 16384 float4s
        ((float4*)xsum)[i] = make_float4(0.f, 0.f, 0.f, 0.f);
    }
}

// ---------------- CSR build ----------------
__global__ __launch_bounds__(256) void scan1_kernel(const int* __restrict__ counts,
                                                    int* __restrict__ row_ptr,
                                                    int* __restrict__ bsums){
    __shared__ int s[256];
    int t = threadIdx.x;
    int i = blockIdx.x * 256 + t;
    int v = (i < NNODES) ? counts[i] : 0;
    s[t] = v; __syncthreads();
    for (int off = 1; off < 256; off <<= 1) {
        int a = (t >= off) ? s[t - off] : 0;
        __syncthreads();
        s[t] += a;
        __syncthreads();
    }
    if (i < NNODES) row_ptr[i] = s[t] - v;
    if (t == 255) bsums[blockIdx.x] = s[255];
}

__global__ __launch_bounds__(512) void scan2_kernel(const int* __restrict__ bsums,
                                                    int* __restrict__ boffs, int nb){
    __shared__ int s[512];
    int t = threadIdx.x;
    int v = (t < nb) ? bsums[t] : 0;
    s[t] = v; __syncthreads();
    for (int off = 1; off < 512; off <<= 1) {
        int a = (t >= off) ? s[t - off] : 0;
        __syncthreads();
        s[t] += a;
        __syncthreads();
    }
    if (t < nb) boffs[t] = s[t] - v;
}

__global__ __launch_bounds__(256) void scan3_kernel(int* __restrict__ row_ptr,
                                                    const int* __restrict__ boffs,
                                                    int* __restrict__ cursor){
    int i = blockIdx.x * 256 + threadIdx.x;
    if (i < NNODES) {
        int r = row_ptr[i] + boffs[blockIdx.x];
        row_ptr[i] = r;
        cursor[i]  = r;
    }
}

__global__ __launch_bounds__(256) void fill_kernel(const int* __restrict__ src,
                                                   const int* __restrict__ tgt,
                                                   int* __restrict__ cursor,
                                                   int* __restrict__ es){
    int e = blockIdx.x * 256 + threadIdx.x;
    if (e < NEDGES) {
        int pos = atomicAdd(&cursor[tgt[e]], 1);
        es[pos] = src[e];
    }
}

// ========== conv MFMA phases, 32x32x16, 32-node tile, K-split us ==========
// xs: 16 planes (8.4 KB). usH: 16 planes (8.4 KB) holding ONE half of U at a
// time. Pass p: compute U-half p -> sync -> accumulate aT over that half
// (K-steps in original order -> bit-exact). LDS 16.9 KB -> 8 blocks/CU.
__device__ __forceinline__ void conv_phases(u16* xs, u16* usH,
                                            const u16* __restrict__ pwg,
                                            const u16* __restrict__ pwe1,
                                            const u16* __restrict__ pwe2,
                                            u16* __restrict__ M, long row0){
    const int t = threadIdx.x;
    const int w = t >> 6, lane = t & 63;
    const int half = lane >> 5, nn = lane & 31;

    f32x16 aT = {};
#pragma unroll
    for (int p = 0; p < 2; p++) {
        // ---- U half-pass: wave w owns ef-tile et = p*4 + w ----
        int et = p * 4 + w;
        short8 A[8];
#pragma unroll
        for (int ks = 0; ks < 8; ks++)
            A[ks] = *(const short8*)(pwe1 + (((ks * 8 + et) * 64 + lane) << 3));
        f32x16 acc = {};
#pragma unroll
        for (int ks = 0; ks < 8; ks++) {
            short8 B = *(const short8*)(&xs[cidx(ks * 2 + half, nn)]);
            acc = __builtin_amdgcn_mfma_f32_32x32x16_bf16(A[ks], B, acc, 0, 0, 0);
        }
#pragma unroll
        for (int q = 0; q < 4; q++) {
            uint2 d;
            d.x = pack2(sp_f(acc[q*4+0]), sp_f(acc[q*4+1]));
            d.y = pack2(sp_f(acc[q*4+2]), sp_f(acc[q*4+3]));
            *(uint2*)(&usH[cidx(w * 4 + q, nn) + half * 4]) = d;
        }
        __syncthreads();
        // ---- C partial: aT += We2^T[h-tile w][K-half p] @ U-half ----
#pragma unroll
        for (int j = 0; j < 8; j++) {
            short8 Ac = *(const short8*)(pwe2 + ((((p * 8 + j) * 4 + w) * 64 + lane) << 3));
            short8 B = *(const short8*)(&usH[cidx(j * 2 + half, nn)]);
            aT = __builtin_amdgcn_mfma_f32_32x32x16_bf16(Ac, B, aT, 0, 0, 0);
        }
        if (p == 0) __syncthreads();               // usH reused by pass 1
    }

    // ---- G phase: aG = Wg^T[h-tile w] @ x^T ----
    f32x16 aG = {};
#pragma unroll
    for (int ks = 0; ks < 8; ks++) {
        short8 A = *(const short8*)(pwg + (((ks * 4 + w) * 64 + lane) << 3));
        short8 B = *(const short8*)(&xs[cidx(ks * 2 + half, nn)]);
        aG = __builtin_amdgcn_mfma_f32_32x32x16_bf16(A, B, aG, 0, 0, 0);
    }
    long node = row0 + nn;                         // 3125*32 == NNODES exactly
#pragma unroll
    for (int q = 0; q < 4; q++) {
        int h0 = w * 32 + half * 4 + q * 8;
        uint2 d;
        d.x = pack2(sig_f(aG[q*4+0]) * sp_f(aT[q*4+0]),
                    sig_f(aG[q*4+1]) * sp_f(aT[q*4+1]));
        d.y = pack2(sig_f(aG[q*4+2]) * sp_f(aT[q*4+2]),
                    sig_f(aG[q*4+3]) * sp_f(aT[q*4+3]));
        *(uint2*)(M + node * HF + h0) = d;
    }
}

// ---------------- conv0: embed fused (vectorized uint4); writes x and M ----------------
__global__ __launch_bounds__(256) void conv0_mfma(const int* __restrict__ nodes,
                                                  const void* __restrict__ emb,
                                                  u16* __restrict__ x,
                                                  const u16* __restrict__ pwg,
                                                  const u16* __restrict__ pwe1,
                                                  const u16* __restrict__ pwe2,
                                                  u16* __restrict__ M){
    __shared__ u16 xs[16 * PLD];   // 8,448 B
    __shared__ u16 us[16 * PLD];   // 8,448 B
    const int t = threadIdx.x;
    const long row0 = (long)blockIdx.x * 32;
    const bool f32 = is_f32(emb);

    for (int i = t; i < 512; i += 256) {           // (row r, chunk q): 16B each
        int r = i >> 4, q = i & 15;
        long node = row0 + r;
        uint4 d = make_uint4(0u, 0u, 0u, 0u);
        if (node < NNODES) {
            int v = nodes[node];
            if (f32) {
                float4 f0 = ((const float4*)emb)[(long)v * 32 + q * 2];
                float4 f1 = ((const float4*)emb)[(long)v * 32 + q * 2 + 1];
                d.x = pack2(f0.x, f0.y); d.y = pack2(f0.z, f0.w);
                d.z = pack2(f1.x, f1.y); d.w = pack2(f1.z, f1.w);
            } else {
                d = ((const uint4*)emb)[(long)v * 16 + q];
            }
            ((uint4*)x)[node * 16 + q] = d;
        }
        *(uint4*)(&xs[cidx(q, r)]) = d;
    }
    __syncthreads();
    conv_phases(xs, us, pwg, pwe1, pwe2, M, row0);
}

// ---------------- conv: stages x from global; writes M ----------------
__global__ __launch_bounds__(256) void conv_mfma(const u16* __restrict__ x,
                                                 const u16* __restrict__ pwg,
                                                 const u16* __restrict__ pwe1,
                                                 const u16* __restrict__ pwe2,
                                                 u16* __restrict__ M){
    __shared__ u16 xs[16 * PLD];
    __shared__ u16 us[16 * PLD];
    const int t = threadIdx.x;
    const long row0 = (long)blockIdx.x * 32;

    for (int i = t; i < 512; i += 256) {
        int r = i >> 4, q = i & 15;
        long node = row0 + r;
        uint4 v = make_uint4(0u, 0u, 0u, 0u);
        if (node < NNODES) v = ((const uint4*)x)[node * 16 + q];
        *(uint4*)(&xs[cidx(q, r)]) = v;
    }
    __syncthreads();
    conv_phases(xs, us, pwg, pwe1, pwe2, M, row0);
}

// -------- agg gather core: fp32 sums of M rows for node v, lane-chunk l --------
__device__ __forceinline__ void agg_gather(const uint4* __restrict__ Mu,
                                           const int* __restrict__ es,
                                           int start, int cnt, int l,
                                           float* a){
    float b0=0.f,b1=0.f,b2=0.f,b3=0.f,b4=0.f,b5=0.f,b6=0.f,b7=0.f;
    int e = 0;
    for (; e + 3 < cnt; e += 4) {
        int s0 = es[start + e],     s1 = es[start + e + 1];
        int s2 = es[start + e + 2], s3 = es[start + e + 3];
        uint4 u0 = Mu[(long)s0 * 16 + l];
        uint4 u1 = Mu[(long)s1 * 16 + l];
        uint4 u2 = Mu[(long)s2 * 16 + l];
        uint4 u3 = Mu[(long)s3 * 16 + l];
        a[0] += bfu((u16)u0.x); a[1] += bfu((u16)(u0.x >> 16));
        a[2] += bfu((u16)u0.y); a[3] += bfu((u16)(u0.y >> 16));
        a[4] += bfu((u16)u0.z); a[5] += bfu((u16)(u0.z >> 16));
        a[6] += bfu((u16)u0.w); a[7] += bfu((u16)(u0.w >> 16));
        b0 += bfu((u16)u1.x); b1 += bfu((u16)(u1.x >> 16));
        b2 += bfu((u16)u1.y); b3 += bfu((u16)(u1.y >> 16));
        b4 += bfu((u16)u1.z); b5 += bfu((u16)(u1.z >> 16));
        b6 += bfu((u16)u1.w); b7 += bfu((u16)(u1.w >> 16));
        a[0] += bfu((u16)u2.x); a[1] += bfu((u16)(u2.x >> 16));
        a[2] += bfu((u16)u2.y); a[3] += bfu((u16)(u2.y >> 16));
        a[4] += bfu((u16)u2.z); a[5] += bfu((u16)(u2.z >> 16));
        a[6] += bfu((u16)u2.w); a[7] += bfu((u16)(u2.w >> 16));
        b0 += bfu((u16)u3.x); b1 += bfu((u16)(u3.x >> 16));
        b2 += bfu((u16)u3.y); b3 += bfu((u16)(u3.y >> 16));
        b4 += bfu((u16)u3.z); b5 += bfu((u16)(u3.z >> 16));
        b6 += bfu((u16)u3.w); b7 += bfu((u16)(u3.w >> 16));
    }
    for (; e < cnt; e++) {
        int s0 = es[start + e];
        uint4 u0 = Mu[(long)s0 * 16 + l];
        a[0] += bfu((u16)u0.x); a[1] += bfu((u16)(u0.x >> 16));
        a[2] += bfu((u16)u0.y); a[3] += bfu((u16)(u0.y >> 16));
        a[4] += bfu((u16)u0.z); a[5] += bfu((u16)(u0.z >> 16));
        a[6] += bfu((u16)u0.w); a[7] += bfu((u16)(u0.w >> 16));
    }
    a[0] += b0; a[1] += b1; a[2] += b2; a[3] += b3;
    a[4] += b4; a[5] += b5; a[6] += b6; a[7] += b7;
}

// ---------------- aggregation (convs 1,2): x[v] += sp( sum M[src] ) ----------------
__global__ __launch_bounds__(256) void agg_kernel(const u16* __restrict__ M,
                                                  const int* __restrict__ row_ptr,
                                                  const int* __restrict__ counts,
                                                  const int* __restrict__ es,
                                                  u16* __restrict__ x){
    int wid = blockIdx.x * 4 + (threadIdx.x >> 6);
    int lane = threadIdx.x & 63;
    long v = (long)wid * 4 + (lane >> 4);
    int l = lane & 15;
    if (v >= NNODES) return;
    float a[8] = {};
    agg_gather((const uint4*)M, es, row_ptr[v], counts[v], l, a);
    uint4* xu = (uint4*)x;
    uint4 xv = xu[v * 16 + l];
    xv.x = pack2(bfu((u16)xv.x) + sp_f(a[0]), bfu((u16)(xv.x >> 16)) + sp_f(a[1]));
    xv.y = pack2(bfu((u16)xv.y) + sp_f(a[2]), bfu((u16)(xv.y >> 16)) + sp_f(a[3]));
    xv.z = pack2(bfu((u16)xv.z) + sp_f(a[4]), bfu((u16)(xv.z >> 16)) + sp_f(a[5]));
    xv.w = pack2(bfu((u16)xv.w) + sp_f(a[6]), bfu((u16)(xv.w >> 16)) + sp_f(a[7]));
    xu[v * 16 + l] = xv;
}

// ---------- fused final agg + pooling: xsum[g] += bf16(x + sp(agg)) ----------
// No x write/read round-trip. Wave's 4 nodes usually share a graph (gidx
// sorted, ~195 nodes/graph) -> cross-lane reduce then 128 atomics/wave.
__global__ __launch_bounds__(256) void aggpool_kernel(const u16* __restrict__ M,
                                                      const int* __restrict__ row_ptr,
                                                      const int* __restrict__ counts,
                                                      const int* __restrict__ es,
                                                      const u16* __restrict__ x,
                                                      const int* __restrict__ gidx,
                                                      float* __restrict__ xsum){
    int wid = blockIdx.x * 4 + (threadIdx.x >> 6);
    int lane = threadIdx.x & 63;
    long v = (long)wid * 4 + (lane >> 4);          // 6250*4*4 == NNODES exactly
    int l = lane & 15;
    float a[8] = {};
    agg_gather((const uint4*)M, es, row_ptr[v], counts[v], l, a);
    uint4 xv = ((const uint4*)x)[v * 16 + l];
    float f[8];
    f[0] = rbf(bfu((u16)xv.x) + sp_f(a[0])); f[1] = rbf(bfu((u16)(xv.x >> 16)) + sp_f(a[1]));
    f[2] = rbf(bfu((u16)xv.y) + sp_f(a[2])); f[3] = rbf(bfu((u16)(xv.y >> 16)) + sp_f(a[3]));
    f[4] = rbf(bfu((u16)xv.z) + sp_f(a[4])); f[5] = rbf(bfu((u16)(xv.z >> 16)) + sp_f(a[5]));
    f[6] = rbf(bfu((u16)xv.w) + sp_f(a[6])); f[7] = rbf(bfu((u16)(xv.w >> 16)) + sp_f(a[7]));

    int g = gidx[v];
    int gx = __shfl_xor(g, 16, 64);
    int gy = __shfl_xor(g, 32, 64);
    int gz = __shfl_xor(g, 48, 64);
    bool same = (g == gx) && (g == gy) && (g == gz);   // wave-uniform
    if (same) {
#pragma unroll
        for (int i = 0; i < 8; i++) {
            f[i] += __shfl_xor(f[i], 16, 64);
            f[i] += __shfl_xor(f[i], 32, 64);
        }
        if (lane < 16) {
#pragma unroll
            for (int i = 0; i < 8; i++)
                atomicAdd(&xsum[g * HF + l * 8 + i], f[i]);
        }
    } else {
#pragma unroll
        for (int i = 0; i < 8; i++)
            atomicAdd(&xsum[g * HF + l * 8 + i], f[i]);
    }
}

// ---------------- head via transposed 16x16 MFMA, bf16 hi+lo activations ----------------
__global__ __launch_bounds__(256) void head_mfma(const float* __restrict__ xsum,
                                                 const void* __restrict__ ncnt,
                                                 const u16* __restrict__ pwp,
                                                 const u16* __restrict__ pf1,
                                                 const u16* __restrict__ pf2,
                                                 const void* __restrict__ bfc1,
                                                 const void* __restrict__ bfc2,
                                                 const void* __restrict__ Wr,
                                                 const void* __restrict__ br,
                                                 void* __restrict__ out,
                                                 const void* __restrict__ probe){
    __shared__ u16 hibuf[2][GB][136];
    __shared__ u16 lobuf[2][GB][136];
    const int t = threadIdx.x;
    const int w = t >> 6, lane = t & 63;
    const int quad = lane >> 4, nr = lane & 15;
    const bool f32 = is_f32(probe);
    const int g0 = blockIdx.x * GB;

    for (int i = t; i < GB * 64; i += 256) {
        int g = i >> 6, c = (i & 63) * 2;
        float f0 = xsum[(g0 + g) * HF + c], f1 = xsum[(g0 + g) * HF + c + 1];
        u16 h0 = f2bf(f0), h1 = f2bf(f1);
        *(unsigned*)&hibuf[0][g][c] = (unsigned)h0 | ((unsigned)h1 << 16);
        *(unsigned*)&lobuf[0][g][c] = pack2(f0 - bfu(h0), f1 - bfu(h1));
    }
    __syncthreads();

    float rc[2];
#pragma unroll
    for (int nt = 0; nt < 2; nt++) rc[nt] = RCP1(lf(ncnt, g0 + nt * 16 + nr, f32));

    int cur = 0;
    for (int layer = 0; layer < 3; layer++) {
        const u16* pw = (layer == 0) ? pwp : (layer == 1) ? pf1 : pf2;
        const void* bias = (layer == 1) ? bfc1 : bfc2;
        int nxt = cur ^ 1;
#pragma unroll
        for (int c = 0; c < 2; c++) {
            int et = w * 2 + c;
            short8 A[4];
#pragma unroll
            for (int kt = 0; kt < 4; kt++)
                A[kt] = *(const short8*)(pw + (((kt * 8 + et) * 64 + lane) << 3));
#pragma unroll
            for (int nt = 0; nt < 2; nt++) {
                f32x4 acc = {0.f, 0.f, 0.f, 0.f};
#pragma unroll
                for (int kt = 0; kt < 4; kt++) {
                    short8 bh = *(const short8*)(&hibuf[cur][nt * 16 + nr][kt * 32 + quad * 8]);
                    short8 bl = *(const short8*)(&lobuf[cur][nt * 16 + nr][kt * 32 + quad * 8]);
                    acc = __builtin_amdgcn_mfma_f32_16x16x32_bf16(A[kt], bh, acc, 0, 0, 0);
                    acc = __builtin_amdgcn_mfma_f32_16x16x32_bf16(A[kt], bl, acc, 0, 0, 0);
                }
                int feat0 = et * 16 + quad * 4;
                float f[4];
#pragma unroll
                for (int r = 0; r < 4; r++) {
                    float a = (layer == 0) ? acc[r] * rc[nt]
                                           : acc[r] + lf(bias, feat0 + r, f32);
                    f[r] = sp_f(a);
                }
                u16 h[4]; float lo[4];
#pragma unroll
                for (int r = 0; r < 4; r++) { h[r] = f2bf(f[r]); lo[r] = f[r] - bfu(h[r]); }
                uint2 dh, dl;
                dh.x = (unsigned)h[0] | ((unsigned)h[1] << 16);
                dh.y = (unsigned)h[2] | ((unsigned)h[3] << 16);
                dl.x = pack2(lo[0], lo[1]);
                dl.y = pack2(lo[2], lo[3]);
                *(uint2*)&hibuf[nxt][nt * 16 + nr][feat0] = dh;
                *(uint2*)&lobuf[nxt][nt * 16 + nr][feat0] = dl;
            }
        }
        __syncthreads();
        cur = nxt;
    }

    int g = t >> 3, sub = t & 7;
    float p = 0.f;
    for (int k = sub * 16; k < sub * 16 + 16; k++) {
        float v = bfu(hibuf[cur][g][k]) + bfu(lobuf[cur][g][k]);
        p += v * lf(Wr, k, f32);
    }
    p += __shfl_down(p, 4, 64);
    p += __shfl_down(p, 2, 64);
    p += __shfl_down(p, 1, 64);
    if (sub == 0) {
        float res = p + lf(br, 0, f32);
        if (f32) ((float*)out)[g0 + g] = res;
        else     ((u16*)out)[g0 + g]  = f2bf(res);
    }
}

extern "C" void kernel_launch(void* const* d_in, const int* in_sizes, int n_in,
                              void* d_out, int out_size, void* d_ws, size_t ws_size,
                              hipStream_t stream) {
    const int* nodes = (const int*)d_in[0];
    const int* esrc  = (const int*)d_in[1];
    const int* etgt  = (const int*)d_in[2];
    const int* gidx  = (const int*)d_in[3];

    size_t off = 0;
    char* w = (char*)d_ws;
    auto take = [&](size_t bytes) -> void* {
        void* p = w + off;
        off = (off + bytes + 255) & ~(size_t)255;
        return p;
    };

    u16* pwg     = (u16*)take((size_t)3 * HF * HF * 2);
    u16* pwe1    = (u16*)take((size_t)3 * HF * EF * 2);
    u16* pwe2    = (u16*)take((size_t)3 * EF * HF * 2);
    u16* pwp     = (u16*)take((size_t)HF * HF * 2);
    u16* pf1     = (u16*)take((size_t)HF * HF * 2);
    u16* pf2     = (u16*)take((size_t)HF * HF * 2);
    int* counts  = (int*)take((size_t)NNODES * 4);
    int* row_ptr = (int*)take((size_t)NNODES * 4);
    int* cursor  = (int*)take((size_t)NNODES * 4);
    int* es      = (int*)take((size_t)NEDGES * 4);
    int* bsums   = (int*)take(2048);
    int* boffs   = (int*)take(2048);
    float* xsum  = (float*)take((size_t)NGRAPHS * HF * 4);
    u16* x       = (u16*)take((size_t)NNODES * HF * 2);
    u16* M       = (u16*)take((size_t)NNODES * HF * 2);

    hipMemsetAsync(counts, 0, (size_t)NNODES * 4, stream);

    // prep: conv repack (960) + head repack (192) + count (2344) + xsum zero (64)
    prep_kernel<<<3560, 256, 0, stream>>>(d_in[6], d_in[7], d_in[8],
                                          d_in[9], d_in[10], d_in[12],
                                          pwg, pwe1, pwe2, pwp, pf1, pf2,
                                          d_in[5], etgt, counts, xsum);

    const int NB_SCAN = (NNODES + 255) / 256;      // 391
    const int NB_EDGE = (NEDGES + 255) / 256;      // 2344
    scan1_kernel<<<NB_SCAN, 256, 0, stream>>>(counts, row_ptr, bsums);
    scan2_kernel<<<1, 512, 0, stream>>>(bsums, boffs, NB_SCAN);
    scan3_kernel<<<NB_SCAN, 256, 0, stream>>>(row_ptr, boffs, cursor);
    fill_kernel<<<NB_EDGE, 256, 0, stream>>>(esrc, etgt, cursor, es);

    const int NBC = (NNODES + 31) / 32;            // 3125
    const int NBA = (NNODES + 15) / 16;            // 6250
    conv0_mfma<<<NBC, 256, 0, stream>>>(nodes, d_in[5], x, pwg, pwe1, pwe2, M);
    agg_kernel<<<NBA, 256, 0, stream>>>(M, row_ptr, counts, es, x);
    conv_mfma<<<NBC, 256, 0, stream>>>(x,
        pwg + (size_t)1 * HF * HF, pwe1 + (size_t)1 * HF * EF, pwe2 + (size_t)1 * EF * HF, M);
    agg_kernel<<<NBA, 256, 0, stream>>>(M, row_ptr, counts, es, x);
    conv_mfma<<<NBC, 256, 0, stream>>>(x,
        pwg + (size_t)2 * HF * HF, pwe1 + (size_t)2 * HF * EF, pwe2 + (size_t)2 * EF * HF, M);
    aggpool_kernel<<<NBA, 256, 0, stream>>>(M, row_ptr, counts, es, x, gidx, xsum);

    head_mfma<<<NGRAPHS / GB, 256, 0, stream>>>(xsum, d_in[4], pwp, pf1, pf2,
                                                d_in[11], d_in[13], d_in[14], d_in[15],
                                                d_out, d_in[5]);
}

// Round 14
// 394.016 us; speedup vs baseline: 1.1439x; 1.1439x over previous
//
#include <hip/hip_runtime.h>
#include <hip/hip_bf16.h>

typedef unsigned short u16;
typedef __attribute__((ext_vector_type(8))) short short8;
typedef __attribute__((ext_vector_type(4))) float f32x4;
typedef __attribute__((ext_vector_type(16))) float f32x16;
typedef __attribute__((ext_vector_type(2))) __bf16 bf16x2;

#define NNODES 100000
#define NEDGES 600000
#define NGRAPHS 512
#define HF 128
#define EF 256
#define GB 32       // graphs per head block

// chunk-major LDS planes, 32-node tiles: plane = 32 rows x 16B + 16B pad
// -> stride 264 u16 (528 B = 132 dwords == 4 banks mod 32)
#define PLD 264
__device__ __forceinline__ int cidx(int chunk, int row){ return chunk * PLD + row * 8; }

__device__ __forceinline__ float bfu(u16 u){ return __uint_as_float(((unsigned)u) << 16); }
__device__ __forceinline__ u16 f2bf(float f){
    unsigned u = __float_as_uint(f);
    unsigned r = (u + 0x7fff + ((u >> 16) & 1)) >> 16;
    return (u16)r;
}
// HW packed f32->bf16 RNE (v_cvt_pk_bf16_f32 on gfx950)
__device__ __forceinline__ unsigned pack2(float a, float b){
    bf16x2 v = { (__bf16)a, (__bf16)b };
    return __builtin_bit_cast(unsigned, v);
}

#if __has_builtin(__builtin_amdgcn_rcpf)
#define RCP1(x) __builtin_amdgcn_rcpf(x)
#else
#define RCP1(x) (1.f / (x))
#endif

// cheap softplus: log(1+exp(x)) direct — safe for |x| << 80 (values here <~20)
__device__ __forceinline__ float sp_f(float x){
    return __logf(1.f + __expf(x));
}
__device__ __forceinline__ float sig_f(float x){
    return RCP1(1.f + __expf(-x));
}
__device__ __forceinline__ float lf(const void* p, long i, bool f32){
    return f32 ? ((const float*)p)[i] : bfu(((const u16*)p)[i]);
}

// in-register dtype detection: probe 256 u16 of the embed table as bf16
__device__ __forceinline__ bool is_f32(const void* probe){
    const u16* p = (const u16*)probe;
    int lane = threadIdx.x & 63;
    int c = 0;
#pragma unroll
    for (int i = 0; i < 4; i++) c += (fabsf(bfu(p[lane * 4 + i])) > 1.0f) ? 1 : 0;
#pragma unroll
    for (int off = 32; off; off >>= 1) c += __shfl_xor(c, off, 64);
    return c > 8;
}

// ---------------- prep: weight repack + edge count + xsum zero ----------------
// conv weights -> 32x32x16 A-frag order: P[ks][nt32][lane][8]; lane l holds
//   W[k = ks*16 + (l>>5)*8 + j][n = nt32*32 + (l&31)], j=0..7  (W^T as A operand)
// head weights -> 16x16x32 frag order.
// blocks [0,960): conv; [960,1152): head; [1152,3496): edge count;
// [3496,3560): zero xsum (64 blocks x 256 x float4)
__global__ __launch_bounds__(256) void prep_kernel(const void* __restrict__ wg,
                                                   const void* __restrict__ we1,
                                                   const void* __restrict__ we2,
                                                   const void* __restrict__ wp,
                                                   const void* __restrict__ wfc1,
                                                   const void* __restrict__ wfc2,
                                                   u16* __restrict__ pwg,
                                                   u16* __restrict__ pwe1,
                                                   u16* __restrict__ pwe2,
                                                   u16* __restrict__ pwp,
                                                   u16* __restrict__ pf1,
                                                   u16* __restrict__ pf2,
                                                   const void* __restrict__ emb,
                                                   const int* __restrict__ tgt,
                                                   int* __restrict__ counts,
                                                   float* __restrict__ xsum){
    int b = blockIdx.x, t = threadIdx.x;
    if (b < 960) {
        bool f32 = is_f32(emb);
        int i = b * 256 + t;                       // < 3*81920
        int c = i / 81920, r = i % 81920;
        const void* src; u16* dst; int N, KN, l;
        if (r < 16384)      { src = wg;  dst = pwg;  N = HF; KN = 16384; l = r; }
        else if (r < 49152) { src = we1; dst = pwe1; N = EF; KN = 32768; l = r - 16384; }
        else                { src = we2; dst = pwe2; N = HF; KN = 32768; l = r - 49152; }
        int j = l & 7, lane = (l >> 3) & 63, rest = l >> 9;
        int NT = N >> 5;
        int nt = rest % NT, ks = rest / NT;
        int k = ks * 16 + (lane >> 5) * 8 + j;
        int n = nt * 32 + (lane & 31);
        long base = (long)c * KN;
        dst[base + l] = f2bf(lf(src, base + (long)k * N + n, f32));
    } else if (b < 1152) {
        bool f32 = is_f32(emb);
        int i = (b - 960) * 256 + t;               // < 3*16384
        int c = i / 16384, l = i % 16384;
        const void* src = (c == 0) ? wp : (c == 1) ? wfc1 : wfc2;
        u16* dst = (c == 0) ? pwp : (c == 1) ? pf1 : pf2;
        int j = l & 7, lane = (l >> 3) & 63, rest = l >> 9;
        int nt = rest & 7, kt = rest >> 3;         // 16x16 layout, N=128
        int k = kt * 32 + (lane >> 4) * 8 + j;
        int n = nt * 16 + (lane & 15);
        dst[l] = f2bf(lf(src, (long)k * HF + n, f32));
    } else if (b < 3496) {
        int e = (b - 1152) * 256 + t;
        if (e < NEDGES) atomicAdd(&counts[tgt[e]], 1);
    } else {
        int i = (b - 3496) * 256 + t;              // < 16384 float4s
        ((float4*)xsum)[i] = make_float4(0.f, 0.f, 0.f, 0.f);
    }
}

// ---------------- CSR build ----------------
__global__ __launch_bounds__(256) void scan1_kernel(const int* __restrict__ counts,
                                                    int* __restrict__ row_ptr,
                                                    int* __restrict__ bsums){
    __shared__ int s[256];
    int t = threadIdx.x;
    int i = blockIdx.x * 256 + t;
    int v = (i < NNODES) ? counts[i] : 0;
    s[t] = v; __syncthreads();
    for (int off = 1; off < 256; off <<= 1) {
        int a = (t >= off) ? s[t - off] : 0;
        __syncthreads();
        s[t] += a;
        __syncthreads();
    }
    if (i < NNODES) row_ptr[i] = s[t] - v;
    if (t == 255) bsums[blockIdx.x] = s[255];
}

__global__ __launch_bounds__(512) void scan2_kernel(const int* __restrict__ bsums,
                                                    int* __restrict__ boffs, int nb){
    __shared__ int s[512];
    int t = threadIdx.x;
    int v = (t < nb) ? bsums[t] : 0;
    s[t] = v; __syncthreads();
    for (int off = 1; off < 512; off <<= 1) {
        int a = (t >= off) ? s[t - off] : 0;
        __syncthreads();
        s[t] += a;
        __syncthreads();
    }
    if (t < nb) boffs[t] = s[t] - v;
}

__global__ __launch_bounds__(256) void scan3_kernel(int* __restrict__ row_ptr,
                                                    const int* __restrict__ boffs,
                                                    int* __restrict__ cursor){
    int i = blockIdx.x * 256 + threadIdx.x;
    if (i < NNODES) {
        int r = row_ptr[i] + boffs[blockIdx.x];
        row_ptr[i] = r;
        cursor[i]  = r;
    }
}

__global__ __launch_bounds__(256) void fill_kernel(const int* __restrict__ src,
                                                   const int* __restrict__ tgt,
                                                   int* __restrict__ cursor,
                                                   int* __restrict__ es){
    int e = blockIdx.x * 256 + threadIdx.x;
    if (e < NEDGES) {
        int pos = atomicAdd(&cursor[tgt[e]], 1);
        es[pos] = src[e];
    }
}

// ========== conv MFMA phases, 32x32x16, 32-node tile, K-split us ==========
// xs: 16 planes (8.4 KB). usH: 16 planes (8.4 KB) holding ONE half of U at a
// time. Pass p: compute U-half p -> sync -> accumulate aT over that half
// (K-steps in original order -> bit-exact). LDS 16.9 KB -> 8 blocks/CU.
__device__ __forceinline__ void conv_phases(u16* xs, u16* usH,
                                            const u16* __restrict__ pwg,
                                            const u16* __restrict__ pwe1,
                                            const u16* __restrict__ pwe2,
                                            u16* __restrict__ M, long row0){
    const int t = threadIdx.x;
    const int w = t >> 6, lane = t & 63;
    const int half = lane >> 5, nn = lane & 31;

    f32x16 aT = {};
#pragma unroll
    for (int p = 0; p < 2; p++) {
        // ---- U half-pass: wave w owns ef-tile et = p*4 + w ----
        int et = p * 4 + w;
        short8 A[8];
#pragma unroll
        for (int ks = 0; ks < 8; ks++)
            A[ks] = *(const short8*)(pwe1 + (((ks * 8 + et) * 64 + lane) << 3));
        f32x16 acc = {};
#pragma unroll
        for (int ks = 0; ks < 8; ks++) {
            short8 B = *(const short8*)(&xs[cidx(ks * 2 + half, nn)]);
            acc = __builtin_amdgcn_mfma_f32_32x32x16_bf16(A[ks], B, acc, 0, 0, 0);
        }
#pragma unroll
        for (int q = 0; q < 4; q++) {
            uint2 d;
            d.x = pack2(sp_f(acc[q*4+0]), sp_f(acc[q*4+1]));
            d.y = pack2(sp_f(acc[q*4+2]), sp_f(acc[q*4+3]));
            *(uint2*)(&usH[cidx(w * 4 + q, nn) + half * 4]) = d;
        }
        __syncthreads();
        // ---- C partial: aT += We2^T[h-tile w][K-half p] @ U-half ----
#pragma unroll
        for (int j = 0; j < 8; j++) {
            short8 Ac = *(const short8*)(pwe2 + ((((p * 8 + j) * 4 + w) * 64 + lane) << 3));
            short8 B = *(const short8*)(&usH[cidx(j * 2 + half, nn)]);
            aT = __builtin_amdgcn_mfma_f32_32x32x16_bf16(Ac, B, aT, 0, 0, 0);
        }
        if (p == 0) __syncthreads();               // usH reused by pass 1
    }

    // ---- G phase: aG = Wg^T[h-tile w] @ x^T ----
    f32x16 aG = {};
#pragma unroll
    for (int ks = 0; ks < 8; ks++) {
        short8 A = *(const short8*)(pwg + (((ks * 4 + w) * 64 + lane) << 3));
        short8 B = *(const short8*)(&xs[cidx(ks * 2 + half, nn)]);
        aG = __builtin_amdgcn_mfma_f32_32x32x16_bf16(A, B, aG, 0, 0, 0);
    }
    long node = row0 + nn;                         // 3125*32 == NNODES exactly
#pragma unroll
    for (int q = 0; q < 4; q++) {
        int h0 = w * 32 + half * 4 + q * 8;
        uint2 d;
        d.x = pack2(sig_f(aG[q*4+0]) * sp_f(aT[q*4+0]),
                    sig_f(aG[q*4+1]) * sp_f(aT[q*4+1]));
        d.y = pack2(sig_f(aG[q*4+2]) * sp_f(aT[q*4+2]),
                    sig_f(aG[q*4+3]) * sp_f(aT[q*4+3]));
        *(uint2*)(M + node * HF + h0) = d;
    }
}

// ---------------- conv0: embed fused (vectorized uint4); writes x and M ----------------
__global__ __launch_bounds__(256) void conv0_mfma(const int* __restrict__ nodes,
                                                  const void* __restrict__ emb,
                                                  u16* __restrict__ x,
                                                  const u16* __restrict__ pwg,
                                                  const u16* __restrict__ pwe1,
                                                  const u16* __restrict__ pwe2,
                                                  u16* __restrict__ M){
    __shared__ u16 xs[16 * PLD];   // 8,448 B
    __shared__ u16 us[16 * PLD];   // 8,448 B
    const int t = threadIdx.x;
    const long row0 = (long)blockIdx.x * 32;
    const bool f32 = is_f32(emb);

    for (int i = t; i < 512; i += 256) {           // (row r, chunk q): 16B each
        int r = i >> 4, q = i & 15;
        long node = row0 + r;
        uint4 d = make_uint4(0u, 0u, 0u, 0u);
        if (node < NNODES) {
            int v = nodes[node];
            if (f32) {
                float4 f0 = ((const float4*)emb)[(long)v * 32 + q * 2];
                float4 f1 = ((const float4*)emb)[(long)v * 32 + q * 2 + 1];
                d.x = pack2(f0.x, f0.y); d.y = pack2(f0.z, f0.w);
                d.z = pack2(f1.x, f1.y); d.w = pack2(f1.z, f1.w);
            } else {
                d = ((const uint4*)emb)[(long)v * 16 + q];
            }
            ((uint4*)x)[node * 16 + q] = d;
        }
        *(uint4*)(&xs[cidx(q, r)]) = d;
    }
    __syncthreads();
    conv_phases(xs, us, pwg, pwe1, pwe2, M, row0);
}

// ---------------- conv: stages x from global; writes M ----------------
__global__ __launch_bounds__(256) void conv_mfma(const u16* __restrict__ x,
                                                 const u16* __restrict__ pwg,
                                                 const u16* __restrict__ pwe1,
                                                 const u16* __restrict__ pwe2,
                                                 u16* __restrict__ M){
    __shared__ u16 xs[16 * PLD];
    __shared__ u16 us[16 * PLD];
    const int t = threadIdx.x;
    const long row0 = (long)blockIdx.x * 32;

    for (int i = t; i < 512; i += 256) {
        int r = i >> 4, q = i & 15;
        long node = row0 + r;
        uint4 v = make_uint4(0u, 0u, 0u, 0u);
        if (node < NNODES) v = ((const uint4*)x)[node * 16 + q];
        *(uint4*)(&xs[cidx(q, r)]) = v;
    }
    __syncthreads();
    conv_phases(xs, us, pwg, pwe1, pwe2, M, row0);
}

// ---------------- aggregation: x[v] += sp( sum_{e: tgt=v} M[src[e]] ) ----------------
// uint4 per lane, 16 lanes per node row, 4 nodes per wave, 4x-unrolled gather.
__global__ __launch_bounds__(256) void agg_kernel(const u16* __restrict__ M,
                                                  const int* __restrict__ row_ptr,
                                                  const int* __restrict__ counts,
                                                  const int* __restrict__ es,
                                                  u16* __restrict__ x){
    int wid = blockIdx.x * 4 + (threadIdx.x >> 6);
    int lane = threadIdx.x & 63;
    long v = (long)wid * 4 + (lane >> 4);
    int l = lane & 15;
    if (v >= NNODES) return;
    int start = row_ptr[v], cnt = counts[v];
    float a0=0.f,a1=0.f,a2=0.f,a3=0.f,a4=0.f,a5=0.f,a6=0.f,a7=0.f;
    float b0=0.f,b1=0.f,b2=0.f,b3=0.f,b4=0.f,b5=0.f,b6=0.f,b7=0.f;
    const uint4* Mu = (const uint4*)M;
    int e = 0;
    for (; e + 3 < cnt; e += 4) {
        int s0 = es[start + e],     s1 = es[start + e + 1];
        int s2 = es[start + e + 2], s3 = es[start + e + 3];
        uint4 u0 = Mu[(long)s0 * 16 + l];
        uint4 u1 = Mu[(long)s1 * 16 + l];
        uint4 u2 = Mu[(long)s2 * 16 + l];
        uint4 u3 = Mu[(long)s3 * 16 + l];
        a0 += bfu((u16)u0.x); a1 += bfu((u16)(u0.x >> 16));
        a2 += bfu((u16)u0.y); a3 += bfu((u16)(u0.y >> 16));
        a4 += bfu((u16)u0.z); a5 += bfu((u16)(u0.z >> 16));
        a6 += bfu((u16)u0.w); a7 += bfu((u16)(u0.w >> 16));
        b0 += bfu((u16)u1.x); b1 += bfu((u16)(u1.x >> 16));
        b2 += bfu((u16)u1.y); b3 += bfu((u16)(u1.y >> 16));
        b4 += bfu((u16)u1.z); b5 += bfu((u16)(u1.z >> 16));
        b6 += bfu((u16)u1.w); b7 += bfu((u16)(u1.w >> 16));
        a0 += bfu((u16)u2.x); a1 += bfu((u16)(u2.x >> 16));
        a2 += bfu((u16)u2.y); a3 += bfu((u16)(u2.y >> 16));
        a4 += bfu((u16)u2.z); a5 += bfu((u16)(u2.z >> 16));
        a6 += bfu((u16)u2.w); a7 += bfu((u16)(u2.w >> 16));
        b0 += bfu((u16)u3.x); b1 += bfu((u16)(u3.x >> 16));
        b2 += bfu((u16)u3.y); b3 += bfu((u16)(u3.y >> 16));
        b4 += bfu((u16)u3.z); b5 += bfu((u16)(u3.z >> 16));
        b6 += bfu((u16)u3.w); b7 += bfu((u16)(u3.w >> 16));
    }
    for (; e < cnt; e++) {
        int s0 = es[start + e];
        uint4 u0 = Mu[(long)s0 * 16 + l];
        a0 += bfu((u16)u0.x); a1 += bfu((u16)(u0.x >> 16));
        a2 += bfu((u16)u0.y); a3 += bfu((u16)(u0.y >> 16));
        a4 += bfu((u16)u0.z); a5 += bfu((u16)(u0.z >> 16));
        a6 += bfu((u16)u0.w); a7 += bfu((u16)(u0.w >> 16));
    }
    a0 += b0; a1 += b1; a2 += b2; a3 += b3;
    a4 += b4; a5 += b5; a6 += b6; a7 += b7;
    uint4* xu = (uint4*)x;
    uint4 xv = xu[v * 16 + l];
    xv.x = pack2(bfu((u16)xv.x) + sp_f(a0), bfu((u16)(xv.x >> 16)) + sp_f(a1));
    xv.y = pack2(bfu((u16)xv.y) + sp_f(a2), bfu((u16)(xv.y >> 16)) + sp_f(a3));
    xv.z = pack2(bfu((u16)xv.z) + sp_f(a4), bfu((u16)(xv.z >> 16)) + sp_f(a5));
    xv.w = pack2(bfu((u16)xv.w) + sp_f(a6), bfu((u16)(xv.w >> 16)) + sp_f(a7));
    xu[v * 16 + l] = xv;
}

// ---------------- pooling: xsum[g] = sum of x rows of graph g (atomic flush) ----------------
__global__ __launch_bounds__(256) void pool_kernel(const u16* __restrict__ x,
                                                   const int* __restrict__ gidx,
                                                   float* __restrict__ xsum){
    int wave = blockIdx.x * 4 + (threadIdx.x >> 6);
    int lane = threadIdx.x & 63;
    long base = (long)wave * 64;
    if (base >= NNODES) return;
    long end = base + 64; if (end > NNODES) end = NNODES;
    const unsigned* xu = (const unsigned*)x;
    int gcur = gidx[base];
    float a0 = 0.f, a1 = 0.f;
    for (long v = base; v < end; v++) {
        int g = gidx[v];                           // wave-uniform
        if (g != gcur) {
            atomicAdd(&xsum[gcur * HF + lane * 2 + 0], a0);
            atomicAdd(&xsum[gcur * HF + lane * 2 + 1], a1);
            a0 = a1 = 0.f; gcur = g;
        }
        unsigned u = xu[v * 64 + lane];
        a0 += bfu((u16)u);
        a1 += bfu((u16)(u >> 16));
    }
    atomicAdd(&xsum[gcur * HF + lane * 2 + 0], a0);
    atomicAdd(&xsum[gcur * HF + lane * 2 + 1], a1);
}

// ---------------- head via transposed 16x16 MFMA, bf16 hi+lo activations ----------------
__global__ __launch_bounds__(256) void head_mfma(const float* __restrict__ xsum,
                                                 const void* __restrict__ ncnt,
                                                 const u16* __restrict__ pwp,
                                                 const u16* __restrict__ pf1,
                                                 const u16* __restrict__ pf2,
                                                 const void* __restrict__ bfc1,
                                                 const void* __restrict__ bfc2,
                                                 const void* __restrict__ Wr,
                                                 const void* __restrict__ br,
                                                 void* __restrict__ out,
                                                 const void* __restrict__ probe){
    __shared__ u16 hibuf[2][GB][136];
    __shared__ u16 lobuf[2][GB][136];
    const int t = threadIdx.x;
    const int w = t >> 6, lane = t & 63;
    const int quad = lane >> 4, nr = lane & 15;
    const bool f32 = is_f32(probe);
    const int g0 = blockIdx.x * GB;

    for (int i = t; i < GB * 64; i += 256) {
        int g = i >> 6, c = (i & 63) * 2;
        float f0 = xsum[(g0 + g) * HF + c], f1 = xsum[(g0 + g) * HF + c + 1];
        u16 h0 = f2bf(f0), h1 = f2bf(f1);
        *(unsigned*)&hibuf[0][g][c] = (unsigned)h0 | ((unsigned)h1 << 16);
        *(unsigned*)&lobuf[0][g][c] = pack2(f0 - bfu(h0), f1 - bfu(h1));
    }
    __syncthreads();

    float rc[2];
#pragma unroll
    for (int nt = 0; nt < 2; nt++) rc[nt] = RCP1(lf(ncnt, g0 + nt * 16 + nr, f32));

    int cur = 0;
    for (int layer = 0; layer < 3; layer++) {
        const u16* pw = (layer == 0) ? pwp : (layer == 1) ? pf1 : pf2;
        const void* bias = (layer == 1) ? bfc1 : bfc2;
        int nxt = cur ^ 1;
#pragma unroll
        for (int c = 0; c < 2; c++) {
            int et = w * 2 + c;
            short8 A[4];
#pragma unroll
            for (int kt = 0; kt < 4; kt++)
                A[kt] = *(const short8*)(pw + (((kt * 8 + et) * 64 + lane) << 3));
#pragma unroll
            for (int nt = 0; nt < 2; nt++) {
                f32x4 acc = {0.f, 0.f, 0.f, 0.f};
#pragma unroll
                for (int kt = 0; kt < 4; kt++) {
                    short8 bh = *(const short8*)(&hibuf[cur][nt * 16 + nr][kt * 32 + quad * 8]);
                    short8 bl = *(const short8*)(&lobuf[cur][nt * 16 + nr][kt * 32 + quad * 8]);
                    acc = __builtin_amdgcn_mfma_f32_16x16x32_bf16(A[kt], bh, acc, 0, 0, 0);
                    acc = __builtin_amdgcn_mfma_f32_16x16x32_bf16(A[kt], bl, acc, 0, 0, 0);
                }
                int feat0 = et * 16 + quad * 4;
                float f[4];
#pragma unroll
                for (int r = 0; r < 4; r++) {
                    float a = (layer == 0) ? acc[r] * rc[nt]
                                           : acc[r] + lf(bias, feat0 + r, f32);
                    f[r] = sp_f(a);
                }
                u16 h[4]; float lo[4];
#pragma unroll
                for (int r = 0; r < 4; r++) { h[r] = f2bf(f[r]); lo[r] = f[r] - bfu(h[r]); }
                uint2 dh, dl;
                dh.x = (unsigned)h[0] | ((unsigned)h[1] << 16);
                dh.y = (unsigned)h[2] | ((unsigned)h[3] << 16);
                dl.x = pack2(lo[0], lo[1]);
                dl.y = pack2(lo[2], lo[3]);
                *(uint2*)&hibuf[nxt][nt * 16 + nr][feat0] = dh;
                *(uint2*)&lobuf[nxt][nt * 16 + nr][feat0] = dl;
            }
        }
        __syncthreads();
        cur = nxt;
    }

    int g = t >> 3, sub = t & 7;
    float p = 0.f;
    for (int k = sub * 16; k < sub * 16 + 16; k++) {
        float v = bfu(hibuf[cur][g][k]) + bfu(lobuf[cur][g][k]);
        p += v * lf(Wr, k, f32);
    }
    p += __shfl_down(p, 4, 64);
    p += __shfl_down(p, 2, 64);
    p += __shfl_down(p, 1, 64);
    if (sub == 0) {
        float res = p + lf(br, 0, f32);
        if (f32) ((float*)out)[g0 + g] = res;
        else     ((u16*)out)[g0 + g]  = f2bf(res);
    }
}

extern "C" void kernel_launch(void* const* d_in, const int* in_sizes, int n_in,
                              void* d_out, int out_size, void* d_ws, size_t ws_size,
                              hipStream_t stream) {
    const int* nodes = (const int*)d_in[0];
    const int* esrc  = (const int*)d_in[1];
    const int* etgt  = (const int*)d_in[2];
    const int* gidx  = (const int*)d_in[3];

    size_t off = 0;
    char* w = (char*)d_ws;
    auto take = [&](size_t bytes) -> void* {
        void* p = w + off;
        off = (off + bytes + 255) & ~(size_t)255;
        return p;
    };

    u16* pwg     = (u16*)take((size_t)3 * HF * HF * 2);
    u16* pwe1    = (u16*)take((size_t)3 * HF * EF * 2);
    u16* pwe2    = (u16*)take((size_t)3 * EF * HF * 2);
    u16* pwp     = (u16*)take((size_t)HF * HF * 2);
    u16* pf1     = (u16*)take((size_t)HF * HF * 2);
    u16* pf2     = (u16*)take((size_t)HF * HF * 2);
    int* counts  = (int*)take((size_t)NNODES * 4);
    int* row_ptr = (int*)take((size_t)NNODES * 4);
    int* cursor  = (int*)take((size_t)NNODES * 4);
    int* es      = (int*)take((size_t)NEDGES * 4);
    int* bsums   = (int*)take(2048);
    int* boffs   = (int*)take(2048);
    float* xsum  = (float*)take((size_t)NGRAPHS * HF * 4);
    u16* x       = (u16*)take((size_t)NNODES * HF * 2);
    u16* M       = (u16*)take((size_t)NNODES * HF * 2);

    hipMemsetAsync(counts, 0, (size_t)NNODES * 4, stream);

    // prep: conv repack (960) + head repack (192) + count (2344) + xsum zero (64)
    prep_kernel<<<3560, 256, 0, stream>>>(d_in[6], d_in[7], d_in[8],
                                          d_in[9], d_in[10], d_in[12],
                                          pwg, pwe1, pwe2, pwp, pf1, pf2,
                                          d_in[5], etgt, counts, xsum);

    const int NB_SCAN = (NNODES + 255) / 256;      // 391
    const int NB_EDGE = (NEDGES + 255) / 256;      // 2344
    scan1_kernel<<<NB_SCAN, 256, 0, stream>>>(counts, row_ptr, bsums);
    scan2_kernel<<<1, 512, 0, stream>>>(bsums, boffs, NB_SCAN);
    scan3_kernel<<<NB_SCAN, 256, 0, stream>>>(row_ptr, boffs, cursor);
    fill_kernel<<<NB_EDGE, 256, 0, stream>>>(esrc, etgt, cursor, es);

    const int NBC = (NNODES + 31) / 32;            // 3125
    const int NBA = (NNODES + 15) / 16;            // 6250
    conv0_mfma<<<NBC, 256, 0, stream>>>(nodes, d_in[5], x, pwg, pwe1, pwe2, M);
    agg_kernel<<<NBA, 256, 0, stream>>>(M, row_ptr, counts, es, x);
    conv_mfma<<<NBC, 256, 0, stream>>>(x,
        pwg + (size_t)1 * HF * HF, pwe1 + (size_t)1 * HF * EF, pwe2 + (size_t)1 * EF * HF, M);
    agg_kernel<<<NBA, 256, 0, stream>>>(M, row_ptr, counts, es, x);
    conv_mfma<<<NBC, 256, 0, stream>>>(x,
        pwg + (size_t)2 * HF * HF, pwe1 + (size_t)2 * HF * EF, pwe2 + (size_t)2 * EF * HF, M);
    agg_kernel<<<NBA, 256, 0, stream>>>(M, row_ptr, counts, es, x);

    pool_kernel<<<(NNODES + 255) / 256, 256, 0, stream>>>(x, gidx, xsum);
    head_mfma<<<NGRAPHS / GB, 256, 0, stream>>>(xsum, d_in[4], pwp, pf1, pf2,
                                                d_in[11], d_in[13], d_in[14], d_in[15],
                                                d_out, d_in[5]);
}